// Round 1
// baseline (642.035 us; speedup 1.0000x reference)
//
#include <hip/hip_runtime.h>
#include <math.h>

#define NTOK  16384   // B*S = 4*4096
#define DDIM  2048
#define NE    64
#define KPW   256     // K per wave (2048 / 8 waves)
#define CHUNK 16

__global__ __launch_bounds__(512) void moe_router_kernel(
    const float* __restrict__ x,
    const float* __restrict__ W,
    float* __restrict__ out)
{
    __shared__ float slab[4][64][NE];   // 64 KB reduction scratch

    const int lane  = threadIdx.x & 63;
    const int wv    = __builtin_amdgcn_readfirstlane(threadIdx.x >> 6); // force SGPR
    const int token = blockIdx.x * 64 + lane;
    const float* __restrict__ xrow = x + (size_t)token * DDIM;
    const int kbeg = wv * KPW;

    float acc[NE];
#pragma unroll
    for (int e = 0; e < NE; ++e) acc[e] = 0.f;

    // double-buffered per-lane x chunks (registers)
    float bufA[CHUNK], bufB[CHUNK];
#pragma unroll
    for (int j = 0; j < CHUNK / 4; ++j)
        *reinterpret_cast<float4*>(&bufA[4 * j]) =
            *reinterpret_cast<const float4*>(xrow + kbeg + 4 * j);

#pragma unroll 1
    for (int c = 0; c < KPW / CHUNK; c += 2) {
        const int k0 = kbeg + c * CHUNK;

        // prefetch B @ k0+CHUNK
#pragma unroll
        for (int j = 0; j < CHUNK / 4; ++j)
            *reinterpret_cast<float4*>(&bufB[4 * j]) =
                *reinterpret_cast<const float4*>(xrow + k0 + CHUNK + 4 * j);

        // compute A @ k0  (W index lane-invariant -> s_load through K$)
#pragma unroll
        for (int e = 0; e < NE; ++e) {
            const float* wrow = W + e * DDIM + k0;
#pragma unroll
            for (int j = 0; j < CHUNK; ++j)
                acc[e] = fmaf(bufA[j], wrow[j], acc[e]);
        }

        // prefetch A @ k0+2*CHUNK (clamped: last iter's load is discarded)
        {
            int kn = k0 + 2 * CHUNK;
            int kp = (kn < kbeg + KPW) ? kn : kbeg;
#pragma unroll
            for (int j = 0; j < CHUNK / 4; ++j)
                *reinterpret_cast<float4*>(&bufA[4 * j]) =
                    *reinterpret_cast<const float4*>(xrow + kp + 4 * j);
        }

        // compute B @ k0+CHUNK
#pragma unroll
        for (int e = 0; e < NE; ++e) {
            const float* wrow = W + e * DDIM + k0 + CHUNK;
#pragma unroll
            for (int j = 0; j < CHUNK; ++j)
                acc[e] = fmaf(bufB[j], wrow[j], acc[e]);
        }
    }

    // ---- tree-reduce the 8 K-split partials through LDS ----
    if (wv >= 4) {
#pragma unroll
        for (int e = 0; e < NE; ++e) slab[wv - 4][lane][e] = acc[e];
    }
    __syncthreads();
    if (wv < 4) {
#pragma unroll
        for (int e = 0; e < NE; ++e) acc[e] += slab[wv][lane][e];
    }
    __syncthreads();
    if (wv == 2 || wv == 3) {
#pragma unroll
        for (int e = 0; e < NE; ++e) slab[wv - 2][lane][e] = acc[e];
    }
    __syncthreads();
    if (wv < 2) {
#pragma unroll
        for (int e = 0; e < NE; ++e) acc[e] += slab[wv][lane][e];
    }
    __syncthreads();
    if (wv == 1) {
#pragma unroll
        for (int e = 0; e < NE; ++e) slab[0][lane][e] = acc[e];
    }
    __syncthreads();

    if (wv == 0) {
#pragma unroll
        for (int e = 0; e < NE; ++e) acc[e] += slab[0][lane][e];

        // softmax (match jax.nn.softmax: sub-max, exp, divide)
        float m = acc[0];
#pragma unroll
        for (int e = 1; e < NE; ++e) m = fmaxf(m, acc[e]);
        float s = 0.f;
#pragma unroll
        for (int e = 0; e < NE; ++e) { acc[e] = expf(acc[e] - m); s += acc[e]; }
#pragma unroll
        for (int e = 0; e < NE; ++e) acc[e] = acc[e] / s;

        // top-2; lax.top_k tie-break = lowest index first -> strict '>' ascending scan
        float v1 = -1.f; int i1 = 0;
#pragma unroll
        for (int e = 0; e < NE; ++e) { if (acc[e] > v1) { v1 = acc[e]; i1 = e; } }
        float v2 = -1.f; int i2 = 0;
#pragma unroll
        for (int e = 0; e < NE; ++e) { if (e != i1 && acc[e] > v2) { v2 = acc[e]; i2 = e; } }

        const float ts = v1 + v2;
        float* out_tp = out;              // top_k_probs  [NTOK][2]
        float* out_ti = out + 2 * NTOK;   // top_k_indices[NTOK][2] (as float values)
        float* out_p  = out + 4 * NTOK;   // probs        [NTOK][NE]

        out_tp[token * 2 + 0] = v1 / ts;
        out_tp[token * 2 + 1] = v2 / ts;
        out_ti[token * 2 + 0] = (float)i1;
        out_ti[token * 2 + 1] = (float)i2;
#pragma unroll
        for (int j = 0; j < NE / 4; ++j) {
            float4 v = make_float4(acc[4 * j], acc[4 * j + 1],
                                   acc[4 * j + 2], acc[4 * j + 3]);
            *reinterpret_cast<float4*>(out_p + (size_t)token * NE + 4 * j) = v;
        }
    }
}

extern "C" void kernel_launch(void* const* d_in, const int* in_sizes, int n_in,
                              void* d_out, int out_size, void* d_ws, size_t ws_size,
                              hipStream_t stream) {
    const float* x = (const float*)d_in[0];
    const float* W = (const float*)d_in[1];
    float* out     = (float*)d_out;
    // 16384 tokens, 64 tokens per block, 8 K-split waves (512 threads) per block
    moe_router_kernel<<<dim3(NTOK / 64), dim3(512), 0, stream>>>(x, W, out);
}

// Round 2
// 357.428 us; speedup vs baseline: 1.7963x; 1.7963x over previous
//
#include <hip/hip_runtime.h>
#include <math.h>

// MoE router: logits = x[16384,2048] @ W^T[2048,64]; softmax; top-2; renorm.
// Compute-bound on the fp32 vector ALU (no fp32 MFMA on CDNA4):
//   4.3 GFLOP / 157 TF = 27.4 us floor;  140 MB / 6.3 TB/s = 22 us mem floor.
//
// Tiling (fixes R1's VGPR spill disaster: acc[64]/lane -> acc[16]/lane):
//   block = 64 tokens, 512 threads = 8 waves
//   wave w: K-half = w>>2, expert group eg = w&3 (16 experts), lane = token
//   W addresses are wave-uniform (readfirstlane) -> s_load via SMEM/K$,
//   zero VALU + zero VMEM cost for the W stream.
//   x staged global->reg->LDS, rows padded to 65 floats (banks (lane+k)%32,
//   conflict-free), two-barrier pipeline so global latency hides under FMAs.

#define NTOK  16384
#define DDIM  2048
#define NE    64
#define TPB   64      // tokens per block
#define KT    64      // k per tile (per half)
#define KHALF 1024
#define NIT   (KHALF / KT)   // 16
#define ROW   65      // KT + 1 pad: LDS banks (lane + k) % 32, conflict-free
#define SLABOFF 0            // epilogue: slab[4][64][17] = 4352 floats
#define LOGOFF  4352         // epilogue: logits[64][65]  = 4160 floats
#define LDS_FLOATS 8512      // 34,048 B; x-tile region is 2*64*65 = 8320 floats

__global__ __launch_bounds__(512, 2) void moe_router_kernel(
    const float* __restrict__ x,
    const float* __restrict__ W,
    float* __restrict__ out)
{
    __shared__ float lds[LDS_FLOATS];

    const int tid  = threadIdx.x;
    const int lane = tid & 63;
    const int wv   = __builtin_amdgcn_readfirstlane(tid >> 6); // uniform wave id
    const int half = wv >> 2;      // K half: 0 -> k in [0,1024), 1 -> [1024,2048)
    const int eg   = wv & 3;       // expert group
    const int e0   = eg * 16;
    const int tok0 = blockIdx.x * TPB;
    const int kb0  = half * KHALF;

    // ---- staging map: thread owns 4 float4 of the 8192-float (2-half) tile ----
    // f = tid + 512*i :  h = f>>10, row r = (f>>4)&63, col c = f&15
    const float* gptr[4];
    int lidx[4];
#pragma unroll
    for (int i = 0; i < 4; ++i) {
        const int f = tid + 512 * i;
        const int h = f >> 10, r = (f >> 4) & 63, c = f & 15;
        gptr[i] = x + (size_t)(tok0 + r) * DDIM + h * KHALF + 4 * c;
        lidx[i] = (h * 64 + r) * ROW + 4 * c;
    }

    // ---- prologue: stage tile 0 ----
    float4 pre[4];
#pragma unroll
    for (int i = 0; i < 4; ++i)
        pre[i] = *reinterpret_cast<const float4*>(gptr[i]);
#pragma unroll
    for (int i = 0; i < 4; ++i) {
        lds[lidx[i] + 0] = pre[i].x;
        lds[lidx[i] + 1] = pre[i].y;
        lds[lidx[i] + 2] = pre[i].z;
        lds[lidx[i] + 3] = pre[i].w;
    }
    __syncthreads();

    float acc[16];
#pragma unroll
    for (int j = 0; j < 16; ++j) acc[j] = 0.f;

    // ---- K loop: 16 tiles of 64 k per half ----
#pragma unroll 1
    for (int t = 0; t < NIT; ++t) {
        // prefetch next tile into regs (global latency hides under compute)
        if (t + 1 < NIT) {
#pragma unroll
            for (int i = 0; i < 4; ++i)
                pre[i] = *reinterpret_cast<const float4*>(gptr[i] + (t + 1) * KT);
        }

        const float* __restrict__ xrow = &lds[(half * 64 + lane) * ROW];
        const float* __restrict__ wcol = W + (size_t)e0 * DDIM + kb0 + t * KT;

#pragma unroll 2
        for (int kh = 0; kh < KT; kh += 4) {
            const float x0 = xrow[kh + 0];
            const float x1 = xrow[kh + 1];
            const float x2 = xrow[kh + 2];
            const float x3 = xrow[kh + 3];
#pragma unroll
            for (int j = 0; j < 16; ++j) {
                // wave-uniform address -> s_load_dwordx4 through the K$
                const float4 w4 =
                    *reinterpret_cast<const float4*>(wcol + (size_t)j * DDIM + kh);
                acc[j] = fmaf(x0, w4.x, acc[j]);
                acc[j] = fmaf(x1, w4.y, acc[j]);
                acc[j] = fmaf(x2, w4.z, acc[j]);
                acc[j] = fmaf(x3, w4.w, acc[j]);
            }
        }
        __syncthreads();   // all reads of tile t done
        if (t + 1 < NIT) {
#pragma unroll
            for (int i = 0; i < 4; ++i) {
                lds[lidx[i] + 0] = pre[i].x;
                lds[lidx[i] + 1] = pre[i].y;
                lds[lidx[i] + 2] = pre[i].z;
                lds[lidx[i] + 3] = pre[i].w;
            }
        }
        __syncthreads();   // tile t+1 visible
    }

    // ---- combine K halves (slab padded to 17: 2-way max, free) ----
    if (half == 1) {
#pragma unroll
        for (int j = 0; j < 16; ++j)
            lds[SLABOFF + (eg * 64 + lane) * 17 + j] = acc[j];
    }
    __syncthreads();
    if (half == 0) {
#pragma unroll
        for (int j = 0; j < 16; ++j)
            acc[j] += lds[SLABOFF + (eg * 64 + lane) * 17 + j];
        // full logits for this token's 16 experts -> logits[64][65]
#pragma unroll
        for (int j = 0; j < 16; ++j)
            lds[LOGOFF + lane * 65 + e0 + j] = acc[j];
    }
    __syncthreads();

    // ---- epilogue: wave 0, lane = token; stream through LDS (no p[64] regs) ----
    if (wv == 0) {
        const int token = tok0 + lane;
        const int base  = LOGOFF + lane * 65;

        float m = lds[base];
#pragma unroll
        for (int e = 1; e < NE; ++e) m = fmaxf(m, lds[base + e]);

        float s = 0.f;
#pragma unroll
        for (int e = 0; e < NE; ++e) {
            const float v = expf(lds[base + e] - m);
            s += v;
            lds[base + e] = v;   // own row, no cross-lane -> no barrier needed
        }

        // top-2: lax.top_k tie-break = lowest index first -> strict '>' scan
        float v1 = -1.f; int i1 = 0;
#pragma unroll
        for (int e = 0; e < NE; ++e) {
            const float v = lds[base + e];
            if (v > v1) { v1 = v; i1 = e; }
        }
        float v2 = -1.f; int i2 = 0;
#pragma unroll
        for (int e = 0; e < NE; ++e) {
            const float v = lds[base + e];
            if (e != i1 && v > v2) { v2 = v; i2 = e; }
        }

        const float ts = v1 + v2;
        float* out_tp = out;              // top_k_probs  [NTOK][2]
        float* out_ti = out + 2 * NTOK;   // top_k_indices[NTOK][2] (float values)
        float* out_p  = out + 4 * NTOK;   // probs        [NTOK][NE]

        out_tp[token * 2 + 0] = v1 / ts;
        out_tp[token * 2 + 1] = v2 / ts;
        out_ti[token * 2 + 0] = (float)i1;
        out_ti[token * 2 + 1] = (float)i2;

#pragma unroll
        for (int j = 0; j < NE / 4; ++j) {
            float4 v = make_float4(lds[base + 4 * j + 0] / s,
                                   lds[base + 4 * j + 1] / s,
                                   lds[base + 4 * j + 2] / s,
                                   lds[base + 4 * j + 3] / s);
            *reinterpret_cast<float4*>(out_p + (size_t)token * NE + 4 * j) = v;
        }
    }
}

extern "C" void kernel_launch(void* const* d_in, const int* in_sizes, int n_in,
                              void* d_out, int out_size, void* d_ws, size_t ws_size,
                              hipStream_t stream) {
    const float* x = (const float*)d_in[0];
    const float* W = (const float*)d_in[1];
    float* out     = (float*)d_out;
    moe_router_kernel<<<dim3(NTOK / TPB), dim3(512), 0, stream>>>(x, W, out);
}